// Round 7
// baseline (371.519 us; speedup 1.0000x reference)
//
#include <hip/hip_runtime.h>
#include <hip/hip_bf16.h>

// ---------------------------------------------------------------------------
// UpSampler: 3x sparse 3^3 conv (MFMA bf16, LDS-staged B) -> fused tconv+dec
// ---------------------------------------------------------------------------
#define NC 100000      // N_COARSE
#define MF 400000      // M_FINE
#define K3 27

typedef __bf16 bf16_t;
typedef bf16_t bf16x8 __attribute__((ext_vector_type(8)));
typedef float  f32x4  __attribute__((ext_vector_type(4)));

// Repacked-weight offsets (elements) inside g_w
#define O_E1 0                       // 27*1*4*512 = 55296
#define O_E2 55296                   // 27*2*4*512 = 110592
#define O_E3 165888                  // 110592
#define O_T  276480                  // 8*2*4*512 = 32768
#define O_D1 309248                  // 2*4*512 = 4096
#define O_D2 313344                  // 2*2*512 = 2048
#define W_TOTAL 315392

__device__ __align__(16) bf16_t g_w[W_TOTAL];
__device__ __align__(16) bf16_t g_x0[(size_t)NC * 32];  // bf16 feats
__device__ __align__(16) bf16_t g_x1[(size_t)NC * 64];
__device__ __align__(16) bf16_t g_x2[(size_t)NC * 64];
__device__ int g_nbrT[(size_t)K3 * NC];                 // transposed rulebook

static __device__ __forceinline__ bf16x8 zero8() {
    bf16x8 v;
#pragma unroll
    for (int i = 0; i < 8; ++i) v[i] = (bf16_t)0.0f;
    return v;
}

// ---------------------------------------------------------------------------
// Fused prep: (a) repack fp32 weights -> bf16 MFMA B-frags; (b) feats fp32 ->
// bf16; (c) transpose nbr [NC,27] -> g_nbrT [27,NC].
// ---------------------------------------------------------------------------
__global__ __launch_bounds__(256) void prep_k(
    const float* __restrict__ W_e1, const float* __restrict__ W_e2,
    const float* __restrict__ W_e3, const float* __restrict__ W_t,
    const float* __restrict__ W_d1, const float* __restrict__ W_d2,
    const float* __restrict__ feats, const int* __restrict__ nbr)
{
    int b = blockIdx.x;
    if (b < 154) {
        int tid = b * 256 + threadIdx.x;
        int lane = tid & 63;
        int f = tid >> 6;            // 0..615
        const float* src; int doff, nt, nc, fb;
        if      (f < 108) { src = W_e1; doff = O_E1; nt = 4; nc = 1; fb = 0;   }
        else if (f < 324) { src = W_e2; doff = O_E2; nt = 4; nc = 2; fb = 108; }
        else if (f < 540) { src = W_e3; doff = O_E3; nt = 4; nc = 2; fb = 324; }
        else if (f < 604) { src = W_t;  doff = O_T;  nt = 4; nc = 2; fb = 540; }
        else if (f < 612) { src = W_d1; doff = O_D1; nt = 4; nc = 2; fb = 604; }
        else              { src = W_d2; doff = O_D2; nt = 2; nc = 2; fb = 612; }
        int lf = f - fb;
        int t  = lf % nt;
        int c  = (lf / nt) % nc;
        int ko = lf / (nt * nc);
        int Cin = nc * 32, Cout = nt * 16;
        int n  = t * 16 + (lane & 15);
        int kb = c * 32 + (lane >> 4) * 8;
        bf16x8 tmp;
#pragma unroll
        for (int j = 0; j < 8; ++j)
            tmp[j] = (bf16_t)src[((size_t)ko * Cin + (kb + j)) * Cout + n];
        *(bf16x8*)(g_w + doff + (size_t)lf * 512 + lane * 8) = tmp;
    } else if (b < 1717) {
        int i = (b - 154) * 256 + threadIdx.x;   // chunk of 8 floats
        if (i < NC * 32 / 8) {
            const f32x4* p = (const f32x4*)(feats + (size_t)i * 8);
            f32x4 lo = p[0], hi = p[1];
            bf16x8 v;
#pragma unroll
            for (int j = 0; j < 4; ++j) { v[j] = (bf16_t)lo[j]; v[j + 4] = (bf16_t)hi[j]; }
            *(bf16x8*)(g_x0 + (size_t)i * 8) = v;
        }
    } else {
        int r = (b - 1717) * 256 + threadIdx.x;
        if (r < NC) {
#pragma unroll
            for (int k = 0; k < K3; ++k)
                g_nbrT[(size_t)k * NC + r] = nbr[(size_t)r * K3 + k];
        }
    }
}

// ---------------------------------------------------------------------------
// Sparse 3^3 conv: 4 waves/block, 64 rows/wave (256 rows/block). B[ko]
// double-buffered in LDS, shared by all 4 waves. Next-ko indices prefetched
// into registers so the gather burst pipelines behind current MFMAs.
// Output via per-wave LDS transpose -> coalesced dwordx4 stores.
// Grid must be a multiple of 8 (XCD swizzle).
// ---------------------------------------------------------------------------
#define TS 72   // transpose row stride (bf16): 144B, 16B-aligned
template <int CH>
__global__ __launch_bounds__(256) void conv_k(
    int w_off,
    const float* __restrict__ bias,  // [64] fp32
    int src_sel, int dst_sel)        // 0 = g_x0, 1 = g_x1, 2 = g_x2
{
    constexpr int CIN = CH * 32;
    const bf16_t* xb = (src_sel == 0) ? g_x0 : (src_sel == 1 ? g_x1 : g_x2);
    bf16_t* y = (dst_sel == 1) ? g_x1 : g_x2;
    const bf16_t* wsrc = g_w + w_off;

    __shared__ __align__(16) bf16_t bB[2][4096];    // <= 8 frags (8 KB) / buf
    __shared__ __align__(16) bf16_t tbuf[4][2304];  // per-wave transpose tile
    int tid = threadIdx.x;
    int wv = tid >> 6, lane = tid & 63;
    int cl = lane & 15, q = lane >> 4;

    int per = gridDim.x >> 3;
    int blk = (blockIdx.x & 7) * per + (blockIdx.x >> 3);
    int base = blk * 256 + wv * 64;

    // stage B[0] cooperatively (CH*256 bf16x8 chunks over 256 threads)
    {
        const bf16x8* s = (const bf16x8*)wsrc;
        bf16x8* d = (bf16x8*)bB[0];
#pragma unroll
        for (int i = 0; i < CH; ++i) d[i * 256 + tid] = s[i * 256 + tid];
    }
    // indices for ko = 0
    int idx[4], idx_n[4];
#pragma unroll
    for (int mt = 0; mt < 4; ++mt) {
        int r = base + mt * 16 + cl;
        idx[mt] = (r < NC) ? g_nbrT[r] : NC;
    }

    f32x4 acc[4][4];
#pragma unroll
    for (int t = 0; t < 4; ++t) {
        float b = bias[t * 16 + cl];
#pragma unroll
        for (int mt = 0; mt < 4; ++mt) acc[mt][t] = (f32x4){b, b, b, b};
    }
    __syncthreads();

    for (int ko = 0; ko < K3; ++ko) {
        int cur = ko & 1;
        if (ko + 1 < K3) {
            // prefetch next B into other buffer + next indices into registers
            const bf16x8* s = (const bf16x8*)(wsrc + (size_t)(ko + 1) * CH * 2048);
            bf16x8* d = (bf16x8*)bB[cur ^ 1];
#pragma unroll
            for (int i = 0; i < CH; ++i) d[i * 256 + tid] = s[i * 256 + tid];
#pragma unroll
            for (int mt = 0; mt < 4; ++mt) {
                int r = base + mt * 16 + cl;
                idx_n[mt] = (r < NC) ? g_nbrT[(size_t)(ko + 1) * NC + r] : NC;
            }
        }
#pragma unroll
        for (int c = 0; c < CH; ++c) {
            bf16x8 bfr[4];
#pragma unroll
            for (int t = 0; t < 4; ++t)
                bfr[t] = *(const bf16x8*)&bB[cur][(c * 4 + t) * 512 + lane * 8];
#pragma unroll
            for (int mt = 0; mt < 4; ++mt) {
                bool valid = (unsigned)idx[mt] < (unsigned)NC;
                int s = valid ? idx[mt] : 0;
                bf16x8 a = *(const bf16x8*)(xb + (size_t)s * CIN + c * 32 + q * 8);
                if (!valid) a = zero8();
#pragma unroll
                for (int t = 0; t < 4; ++t)
                    acc[mt][t] = __builtin_amdgcn_mfma_f32_16x16x32_bf16(
                        a, bfr[t], acc[mt][t], 0, 0, 0);
            }
        }
        __syncthreads();
#pragma unroll
        for (int mt = 0; mt < 4; ++mt) idx[mt] = idx_n[mt];
    }

    // relu -> per-wave LDS transpose -> coalesced dwordx4 stores.
    bf16_t* tb = tbuf[wv];
#pragma unroll
    for (int ch = 0; ch < 2; ++ch) {
#pragma unroll
        for (int mt2 = 0; mt2 < 2; ++mt2)
#pragma unroll
            for (int t = 0; t < 4; ++t)
#pragma unroll
                for (int r = 0; r < 4; ++r) {
                    float v = acc[ch * 2 + mt2][t][r];
                    v = v > 0.0f ? v : 0.0f;
                    tb[(mt2 * 16 + q * 4 + r) * TS + t * 16 + cl] = (bf16_t)v;
                }
#pragma unroll
        for (int i = 0; i < 4; ++i) {
            int rl = i * 8 + (lane >> 3);      // 0..31
            int c8 = (lane & 7) * 8;
            bf16x8 v8 = *(const bf16x8*)&tb[rl * TS + c8];
            int orow = base + ch * 32 + rl;
            if (orow < NC)
                *(bf16x8*)(y + (size_t)orow * 64 + c8) = v8;
        }
    }
}

// ---------------------------------------------------------------------------
// Fused tconv + decoder, parent-centric (parent_idx[f] == f>>2 structurally).
// One wave = 16 parents = 64 fine rows. D1/D2 staged once in block LDS
// (removes per-mt global frag re-reads); x_up prefetched at entry (32 VGPR,
// still far from r5's 140-VGPR cliff). Per-wave LDS h-tile, no barriers
// after the initial staging sync. Grid must be a multiple of 8.
// ---------------------------------------------------------------------------
#define HS 72   // bf16 tile row stride (144 B) == 36-float rows
__global__ __launch_bounds__(256) void tconv_dec_k(
    const int*   __restrict__ offs,   // [MF]
    const float* __restrict__ b_t,
    const float* __restrict__ b_d1,
    const float* __restrict__ b_d2,
    const float* __restrict__ x_up,   // [MF, 32] fp32
    float*       __restrict__ out)    // [MF, 32] fp32
{
    __shared__ __align__(16) bf16_t h_lds[4][64 * HS];   // 9216 B / wave
    __shared__ __align__(16) bf16_t dW[6144];            // D1 (4096) + D2 (2048)
    __shared__ __align__(16) int off_lds[4][64];
    int wv = threadIdx.x >> 6, lane = threadIdx.x & 63;
    int cl = lane & 15, q = lane >> 4;
    int per = gridDim.x >> 3;
    int blk = (blockIdx.x & 7) * per + (blockIdx.x >> 3);
    int p0 = (blk * 4 + wv) * 16;
    int fbase = p0 * 4;

    // prefetch x_up immediately (independent; 8 coalesced float4 in flight)
    f32x4 xu[8];
#pragma unroll
    for (int i = 0; i < 8; ++i) {
        int rl = i * 8 + (lane >> 3);
        int c4 = (lane & 7) * 4;
        int fg = fbase + rl;
        if (fg < MF) xu[i] = *(const f32x4*)(x_up + (size_t)fg * 32 + c4);
        else xu[i] = (f32x4){0.0f, 0.0f, 0.0f, 0.0f};
    }

    // stage decoder weights into block LDS (768 chunks / 256 threads)
    {
        const bf16x8* s = (const bf16x8*)(g_w + O_D1);
        bf16x8* d = (bf16x8*)dW;
#pragma unroll
        for (int i = 0; i < 3; ++i) d[i * 256 + threadIdx.x] = s[i * 256 + threadIdx.x];
    }
    // stage the 64 children's offsets (per-wave)
    {
        int fi = fbase + lane;
        off_lds[wv][lane] = (fi < MF) ? offs[fi] : 0;
    }
    __syncthreads();

    // per-m code: nibble at position k = (child j)+1 where offs[4m+j]==k
    int code[4];
#pragma unroll
    for (int r = 0; r < 4; ++r) {
        int4 o = *(const int4*)&off_lds[wv][(q * 4 + r) * 4];
        code[r] = (1 << (4 * o.x)) | (2 << (4 * o.y)) |
                  (3 << (4 * o.z)) | (4 << (4 * o.w));
    }

    // load X A-frags (parents p0+cl, rows of g_x1)
    bool pv = (p0 + cl) < NC;
    size_t xrow = (size_t)(pv ? p0 + cl : 0) * 64;
    bf16x8 ax[2];
#pragma unroll
    for (int c = 0; c < 2; ++c) {
        bf16x8 t8 = *(const bf16x8*)(g_x1 + xrow + c * 32 + q * 8);
        ax[c] = pv ? t8 : zero8();
    }

    const bf16_t* wt = g_w + O_T;
#pragma unroll
    for (int k = 0; k < 8; ++k) {
        f32x4 acc[4];
#pragma unroll
        for (int t = 0; t < 4; ++t) {
            float b = b_t[t * 16 + cl];
            acc[t] = (f32x4){b, b, b, b};
        }
#pragma unroll
        for (int c = 0; c < 2; ++c) {
            const bf16_t* wb = wt + ((size_t)(k * 2 + c) * 4) * 512 + lane * 8;
#pragma unroll
            for (int t = 0; t < 4; ++t) {
                bf16x8 b = *(const bf16x8*)(wb + t * 512);
                acc[t] = __builtin_amdgcn_mfma_f32_16x16x32_bf16(ax[c], b, acc[t], 0, 0, 0);
            }
        }
        // scatter selected child rows into h1 tile (per-wave)
#pragma unroll
        for (int r = 0; r < 4; ++r) {
            int nib = (code[r] >> (4 * k)) & 0xF;
            if (nib) {
                int fl = (((q * 4 + r) * 4) + (nib - 1)) & 63;
#pragma unroll
                for (int t = 0; t < 4; ++t) {
                    float v = acc[t][r];
                    v = v > 0.0f ? v : 0.0f;
                    h_lds[wv][fl * HS + t * 16 + cl] = (bf16_t)v;
                }
            }
        }
    }

    // ---- decoder stage 1: h2 = relu(h1) @ W_d1 + b_d1 ----
    bf16x8 a1[4][2];
#pragma unroll
    for (int mt = 0; mt < 4; ++mt)
#pragma unroll
        for (int c = 0; c < 2; ++c)
            a1[mt][c] = *(const bf16x8*)&h_lds[wv][(mt * 16 + cl) * HS + c * 32 + q * 8];

#pragma unroll
    for (int mt = 0; mt < 4; ++mt) {
        f32x4 acc2[4];
#pragma unroll
        for (int t = 0; t < 4; ++t) {
            float b = b_d1[t * 16 + cl];
            acc2[t] = (f32x4){b, b, b, b};
        }
#pragma unroll
        for (int c = 0; c < 2; ++c)
#pragma unroll
            for (int t = 0; t < 4; ++t) {
                bf16x8 b = *(const bf16x8*)&dW[(size_t)(c * 4 + t) * 512 + lane * 8];
                acc2[t] = __builtin_amdgcn_mfma_f32_16x16x32_bf16(a1[mt][c], b, acc2[t], 0, 0, 0);
            }
#pragma unroll
        for (int t = 0; t < 4; ++t)
#pragma unroll
            for (int r = 0; r < 4; ++r) {
                float v = acc2[t][r];
                v = v > 0.0f ? v : 0.0f;
                h_lds[wv][(mt * 16 + q * 4 + r) * HS + t * 16 + cl] = (bf16_t)v;
            }
    }

    // ---- decoder stage 2: h3 = relu(h2) @ W_d2 + b_d2, fp32 into same rows --
    float* fW = (float*)h_lds[wv];
#pragma unroll
    for (int mt = 0; mt < 4; ++mt) {
        bf16x8 a2[2];
#pragma unroll
        for (int c = 0; c < 2; ++c)
            a2[c] = *(const bf16x8*)&h_lds[wv][(mt * 16 + cl) * HS + c * 32 + q * 8];
        f32x4 acc3[2];
#pragma unroll
        for (int t = 0; t < 2; ++t) {
            float b = b_d2[t * 16 + cl];
            acc3[t] = (f32x4){b, b, b, b};
        }
#pragma unroll
        for (int c = 0; c < 2; ++c)
#pragma unroll
            for (int t = 0; t < 2; ++t) {
                bf16x8 b = *(const bf16x8*)&dW[4096 + (size_t)(c * 2 + t) * 512 + lane * 8];
                acc3[t] = __builtin_amdgcn_mfma_f32_16x16x32_bf16(a2[c], b, acc3[t], 0, 0, 0);
            }
#pragma unroll
        for (int t = 0; t < 2; ++t)
#pragma unroll
            for (int r = 0; r < 4; ++r)
                fW[(mt * 16 + q * 4 + r) * 36 + t * 16 + cl] = acc3[t][r];
    }

    // ---- coalesced epilogue: out = h3 + x_up (float4/lane) ----
#pragma unroll
    for (int i = 0; i < 8; ++i) {
        int rl = i * 8 + (lane >> 3);
        int c4 = (lane & 7) * 4;
        int fg = fbase + rl;
        if (fg < MF) {
            f32x4 v = *(const f32x4*)&fW[rl * 36 + c4];
            v += xu[i];
            *(f32x4*)(out + (size_t)fg * 32 + c4) = v;
        }
    }
}

// ---------------------------------------------------------------------------
extern "C" void kernel_launch(void* const* d_in, const int* in_sizes, int n_in,
                              void* d_out, int out_size, void* d_ws, size_t ws_size,
                              hipStream_t stream) {
    const float* feats  = (const float*)d_in[0];
    const float* x_up   = (const float*)d_in[1];
    const int*   nbr    = (const int*)d_in[2];
    const int*   offs   = (const int*)d_in[4];
    const float* W_e1 = (const float*)d_in[5];
    const float* b_e1 = (const float*)d_in[6];
    const float* W_e2 = (const float*)d_in[7];
    const float* b_e2 = (const float*)d_in[8];
    const float* W_e3 = (const float*)d_in[9];
    const float* b_e3 = (const float*)d_in[10];
    const float* W_t  = (const float*)d_in[11];
    const float* b_t  = (const float*)d_in[12];
    const float* W_d1 = (const float*)d_in[13];
    const float* b_d1 = (const float*)d_in[14];
    const float* W_d2 = (const float*)d_in[15];
    const float* b_d2 = (const float*)d_in[16];
    float* out = (float*)d_out;

    // prep: 154 repack + 1563 feats + 391 nbr-transpose blocks
    prep_k<<<2108, 256, 0, stream>>>(W_e1, W_e2, W_e3, W_t, W_d1, W_d2, feats, nbr);

    // conv: 4 waves/block, 64 rows/wave -> 256 rows/block
    // ceil(100000/256)=391 -> pad 392 (multiple of 8)
    conv_k<1><<<392, 256, 0, stream>>>(O_E1, b_e1, 0, 1);
    conv_k<2><<<392, 256, 0, stream>>>(O_E2, b_e2, 1, 2);
    conv_k<2><<<392, 256, 0, stream>>>(O_E3, b_e3, 2, 1);

    // tconv+decoder: 16 parents/wave -> ceil(6250/4)=1563 -> pad 1568 (x8)
    tconv_dec_k<<<1568, 256, 0, stream>>>(offs, b_t, b_d1, b_d2, x_up, out);
}